// Round 1
// baseline (266.663 us; speedup 1.0000x reference)
//
#include <hip/hip_runtime.h>
#include <hip/hip_bf16.h>
#include <cstdint>
#include <cstddef>

#define B_ 2
#define T_ 2048
#define C_ 1024
#define H_ 16
#define D_ 64

typedef unsigned short u16;
typedef unsigned int u32;

typedef __bf16 bf16x8 __attribute__((ext_vector_type(8)));
typedef float f32x4 __attribute__((ext_vector_type(4)));

union BFQ {
    uint4 q;
    bf16x8 v;
    u16 s[8];
};

__device__ __forceinline__ u16 f2bf(float f) {
    union { float f; u32 u; } x;
    x.f = f;
    u32 u = x.u;
    return (u16)((u + 0x7FFFu + ((u >> 16) & 1u)) >> 16);
}

// ---------------- fp32 -> bf16 conversion (vectorized) ----------------
__global__ void cvt_kernel(const float* __restrict__ in, u16* __restrict__ out, int n4) {
    int i = blockIdx.x * blockDim.x + threadIdx.x;
    int stride = gridDim.x * blockDim.x;
    for (; i < n4; i += stride) {
        float4 f = reinterpret_cast<const float4*>(in)[i];
        ushort4 o;
        o.x = f2bf(f.x);
        o.y = f2bf(f.y);
        o.z = f2bf(f.z);
        o.w = f2bf(f.w);
        reinterpret_cast<ushort4*>(out)[i] = o;
    }
}

// ---------------- GEMM: C[m,n] = sum_k A[m,k]*Bw[n,k] + bias[n] ----------------
// A: M x K bf16 row-major; Bw: N x K bf16 row-major (i.e. X @ W^T pattern).
// 128x128 tile, BK=64, 256 threads (4 waves as 2x2), 16x16x32 bf16 MFMA.
#define LDK 72  // padded LDS row stride (elements)

template <int OUT_BF16>
__global__ __launch_bounds__(256, 2) void gemm_bt(const u16* __restrict__ A,
                                                  const u16* __restrict__ Bw,
                                                  const float* __restrict__ bias,
                                                  void* __restrict__ Cout,
                                                  int M, int N, int K) {
    __shared__ u16 As[128 * LDK];
    __shared__ u16 Bs[128 * LDK];

    const int tid = threadIdx.x;
    const int lane = tid & 63;
    const int wave = tid >> 6;
    const int wm = wave >> 1, wn = wave & 1;
    const int g = lane >> 4, r = lane & 15;
    const int m0 = blockIdx.y * 128, n0 = blockIdx.x * 128;

    f32x4 acc[4][4] = {};

    // staging: thread covers row = tid>>1 (0..127), half = tid&1 (32 elems = 64B)
    const int srow = tid >> 1;
    const int shalf = tid & 1;
    const u16* arow = A + (size_t)(m0 + srow) * K + shalf * 32;
    const u16* brow = Bw + (size_t)(n0 + srow) * K + shalf * 32;
    u16* asdst = As + srow * LDK + shalf * 32;
    u16* bsdst = Bs + srow * LDK + shalf * 32;

    for (int k0 = 0; k0 < K; k0 += 64) {
        __syncthreads();
        uint4 a0 = *(const uint4*)(arow + k0);
        uint4 a1 = *(const uint4*)(arow + k0 + 8);
        uint4 a2 = *(const uint4*)(arow + k0 + 16);
        uint4 a3 = *(const uint4*)(arow + k0 + 24);
        uint4 b0 = *(const uint4*)(brow + k0);
        uint4 b1 = *(const uint4*)(brow + k0 + 8);
        uint4 b2 = *(const uint4*)(brow + k0 + 16);
        uint4 b3 = *(const uint4*)(brow + k0 + 24);
        *(uint4*)(asdst + 0) = a0;
        *(uint4*)(asdst + 8) = a1;
        *(uint4*)(asdst + 16) = a2;
        *(uint4*)(asdst + 24) = a3;
        *(uint4*)(bsdst + 0) = b0;
        *(uint4*)(bsdst + 8) = b1;
        *(uint4*)(bsdst + 16) = b2;
        *(uint4*)(bsdst + 24) = b3;
        __syncthreads();

#pragma unroll
        for (int kk = 0; kk < 2; ++kk) {
            bf16x8 af[4], bfv[4];
#pragma unroll
            for (int mt = 0; mt < 4; ++mt) {
                BFQ u;
                u.q = *(const uint4*)(As + (wm * 64 + mt * 16 + r) * LDK + kk * 32 + g * 8);
                af[mt] = u.v;
            }
#pragma unroll
            for (int nt = 0; nt < 4; ++nt) {
                BFQ u;
                u.q = *(const uint4*)(Bs + (wn * 64 + nt * 16 + r) * LDK + kk * 32 + g * 8);
                bfv[nt] = u.v;
            }
#pragma unroll
            for (int mt = 0; mt < 4; ++mt)
#pragma unroll
                for (int nt = 0; nt < 4; ++nt)
                    acc[mt][nt] = __builtin_amdgcn_mfma_f32_16x16x32_bf16(af[mt], bfv[nt], acc[mt][nt], 0, 0, 0);
        }
    }

    // epilogue: D layout col=lane&15, row=(lane>>4)*4+j
#pragma unroll
    for (int mt = 0; mt < 4; ++mt) {
#pragma unroll
        for (int nt = 0; nt < 4; ++nt) {
            int n = n0 + wn * 64 + nt * 16 + r;
            float bv = bias[n];
#pragma unroll
            for (int j = 0; j < 4; ++j) {
                int m = m0 + wm * 64 + mt * 16 + g * 4 + j;
                float val = acc[mt][nt][j] + bv;
                if (OUT_BF16)
                    ((u16*)Cout)[(size_t)m * N + n] = f2bf(val);
                else
                    ((float*)Cout)[(size_t)m * N + n] = val;
            }
        }
    }
}

// ---------------- causal flash attention ----------------
// grid: (T/64, B*H). block: 256 threads = 4 waves, each wave owns 16 q-rows.
__global__ __launch_bounds__(256, 2) void attn_kernel(const u16* __restrict__ Qp,
                                                      const u16* __restrict__ Kp,
                                                      const u16* __restrict__ Vp,
                                                      u16* __restrict__ Op) {
    __shared__ u16 Ks[64 * 72];      // [kv][d] padded
    __shared__ u16 Vt[64 * 72];      // [d][kv] padded (transposed)
    __shared__ u16 Pl[4][16 * 72];   // per-wave P transpose buffer [q][kv]

    const int tid = threadIdx.x, lane = tid & 63, wave = tid >> 6;
    const int g = lane >> 4, r = lane & 15;
    const int bh = blockIdx.y, b = bh >> 4, h = bh & 15;
    const int q0 = blockIdx.x * 64;

    // hoist Q fragments: A-frag row = lane&15 -> q row = q0 + wave*16 + r
    bf16x8 a_q[2];
    {
        const u16* qbase = Qp + ((size_t)(b * T_ + q0 + wave * 16 + r) * C_ + h * 64 + g * 8);
        BFQ u0, u1;
        u0.q = *(const uint4*)(qbase);
        u1.q = *(const uint4*)(qbase + 32);
        a_q[0] = u0.v;
        a_q[1] = u1.v;
    }

    float m_run[4], l_run[4];
    f32x4 o_acc[4] = {};
#pragma unroll
    for (int j = 0; j < 4; ++j) {
        m_run[j] = -1e30f;
        l_run[j] = 0.f;
    }

    const int sr = tid >> 2;   // 0..63 staging row
    const int sq = tid & 3;    // quarter of the 64-wide row
    const u16* kgbase = Kp + ((size_t)(b * T_) * C_ + h * 64);
    const u16* vgbase = Vp + ((size_t)(b * T_) * C_ + h * 64);

    for (int kv0 = 0; kv0 <= q0; kv0 += 64) {
        __syncthreads();  // protect previous iteration's LDS reads
        {
            const u16* kr_ = kgbase + (size_t)(kv0 + sr) * C_ + sq * 16;
            uint4 ka = *(const uint4*)(kr_);
            uint4 kb2 = *(const uint4*)(kr_ + 8);
            *(uint4*)(Ks + sr * 72 + sq * 16) = ka;
            *(uint4*)(Ks + sr * 72 + sq * 16 + 8) = kb2;
            const u16* vr_ = vgbase + (size_t)(kv0 + sr) * C_ + sq * 16;
            BFQ va, vb;
            va.q = *(const uint4*)(vr_);
            vb.q = *(const uint4*)(vr_ + 8);
#pragma unroll
            for (int i = 0; i < 8; ++i) {
                Vt[(sq * 16 + i) * 72 + sr] = va.s[i];
                Vt[(sq * 16 + 8 + i) * 72 + sr] = vb.s[i];
            }
        }
        __syncthreads();

        // S = Q K^T (16 q-rows x 64 kv-cols per wave)
        f32x4 s[4] = {};
#pragma unroll
        for (int kk = 0; kk < 2; ++kk) {
#pragma unroll
            for (int nt = 0; nt < 4; ++nt) {
                BFQ u;
                u.q = *(const uint4*)(Ks + (nt * 16 + r) * 72 + kk * 32 + g * 8);
                s[nt] = __builtin_amdgcn_mfma_f32_16x16x32_bf16(a_q[kk], u.v, s[nt], 0, 0, 0);
            }
        }

        // scale + causal mask. D layout: row(q)=g*4+j, col(kv)=r (+16*nt)
        float sv[4][4];
#pragma unroll
        for (int nt = 0; nt < 4; ++nt) {
            int kg = kv0 + nt * 16 + r;
#pragma unroll
            for (int j = 0; j < 4; ++j) {
                int qg = q0 + wave * 16 + g * 4 + j;
                float x = s[nt][j] * 0.125f;
                sv[nt][j] = (kg <= qg) ? x : -1e30f;
            }
        }

        // online softmax, wave-parallel (16-lane column groups)
        float pout[4][4];
#pragma unroll
        for (int j = 0; j < 4; ++j) {
            float rm = fmaxf(fmaxf(sv[0][j], sv[1][j]), fmaxf(sv[2][j], sv[3][j]));
            rm = fmaxf(rm, __shfl_xor(rm, 1));
            rm = fmaxf(rm, __shfl_xor(rm, 2));
            rm = fmaxf(rm, __shfl_xor(rm, 4));
            rm = fmaxf(rm, __shfl_xor(rm, 8));
            float mnew = fmaxf(m_run[j], rm);
            float fac = __expf(m_run[j] - mnew);
            float rs = 0.f;
#pragma unroll
            for (int nt = 0; nt < 4; ++nt) {
                float p = __expf(sv[nt][j] - mnew);
                pout[nt][j] = p;
                rs += p;
            }
            rs += __shfl_xor(rs, 1);
            rs += __shfl_xor(rs, 2);
            rs += __shfl_xor(rs, 4);
            rs += __shfl_xor(rs, 8);
            l_run[j] = l_run[j] * fac + rs;
            m_run[j] = mnew;
#pragma unroll
            for (int nt = 0; nt < 4; ++nt) o_acc[nt][j] *= fac;
        }

        // write P (bf16) to per-wave LDS, transposing into A-frag layout
        u16* pl = Pl[wave];
#pragma unroll
        for (int nt = 0; nt < 4; ++nt)
#pragma unroll
            for (int j = 0; j < 4; ++j)
                pl[(g * 4 + j) * 72 + nt * 16 + r] = f2bf(pout[nt][j]);
        asm volatile("s_waitcnt lgkmcnt(0)" ::: "memory");

        // O += P V
#pragma unroll
        for (int kk = 0; kk < 2; ++kk) {
            BFQ ua;
            ua.q = *(const uint4*)(pl + r * 72 + kk * 32 + g * 8);
            bf16x8 ap = ua.v;
#pragma unroll
            for (int nt = 0; nt < 4; ++nt) {
                BFQ uv;
                uv.q = *(const uint4*)(Vt + (nt * 16 + r) * 72 + kk * 32 + g * 8);
                o_acc[nt] = __builtin_amdgcn_mfma_f32_16x16x32_bf16(ap, uv.v, o_acc[nt], 0, 0, 0);
            }
        }
    }

    // epilogue: normalize and store bf16 into [B,T,C] head-interleaved layout
#pragma unroll
    for (int nt = 0; nt < 4; ++nt) {
#pragma unroll
        for (int j = 0; j < 4; ++j) {
            int qg = q0 + wave * 16 + g * 4 + j;
            float val = o_acc[nt][j] / l_run[j];
            Op[(size_t)(b * T_ + qg) * C_ + h * 64 + nt * 16 + r] = f2bf(val);
        }
    }
}

// ---------------- launcher ----------------
extern "C" void kernel_launch(void* const* d_in, const int* in_sizes, int n_in,
                              void* d_out, int out_size, void* d_ws, size_t ws_size,
                              hipStream_t stream) {
    const float* q = (const float*)d_in[0];
    const float* k = (const float*)d_in[1];
    const float* v = (const float*)d_in[2];
    // d_in[3] = mask (tril, known causal) - unused
    const float* Wq = (const float*)d_in[4];
    const float* bq = (const float*)d_in[5];
    const float* Wk = (const float*)d_in[6];
    const float* bk = (const float*)d_in[7];
    const float* Wv = (const float*)d_in[8];
    const float* bv = (const float*)d_in[9];
    const float* Wo = (const float*)d_in[10];
    const float* bo = (const float*)d_in[11];

    const size_t NTC = (size_t)B_ * T_ * C_;  // 4,194,304
    const size_t NW = (size_t)C_ * C_;        // 1,048,576

    char* ws = (char*)d_ws;
    size_t off = 0;
    u16* qb = (u16*)(ws + off);  off += NTC * 2;
    u16* kb = (u16*)(ws + off);  off += NTC * 2;
    u16* vb = (u16*)(ws + off);  off += NTC * 2;
    u16* Wqb = (u16*)(ws + off); off += NW * 2;
    u16* Wkb = (u16*)(ws + off); off += NW * 2;
    u16* Wvb = (u16*)(ws + off); off += NW * 2;
    u16* Wob = (u16*)(ws + off); off += NW * 2;
    u16* Qp = (u16*)(ws + off);  off += NTC * 2;
    u16* Kp = (u16*)(ws + off);  off += NTC * 2;
    u16* Vp = (u16*)(ws + off);  off += NTC * 2;
    u16* AOb = (u16*)(ws + off); off += NTC * 2;

    // 1) convert inputs + weights to bf16
    cvt_kernel<<<1024, 256, 0, stream>>>(q, qb, (int)(NTC / 4));
    cvt_kernel<<<1024, 256, 0, stream>>>(k, kb, (int)(NTC / 4));
    cvt_kernel<<<1024, 256, 0, stream>>>(v, vb, (int)(NTC / 4));
    cvt_kernel<<<1024, 256, 0, stream>>>(Wq, Wqb, (int)(NW / 4));
    cvt_kernel<<<1024, 256, 0, stream>>>(Wk, Wkb, (int)(NW / 4));
    cvt_kernel<<<1024, 256, 0, stream>>>(Wv, Wvb, (int)(NW / 4));
    cvt_kernel<<<1024, 256, 0, stream>>>(Wo, Wob, (int)(NW / 4));

    const int M = B_ * T_;  // 4096
    dim3 ggrid(C_ / 128, M / 128);  // (8, 32)

    // 2) QKV projections (bf16 out)
    gemm_bt<1><<<ggrid, 256, 0, stream>>>(qb, Wqb, bq, Qp, M, C_, C_);
    gemm_bt<1><<<ggrid, 256, 0, stream>>>(kb, Wkb, bk, Kp, M, C_, C_);
    gemm_bt<1><<<ggrid, 256, 0, stream>>>(vb, Wvb, bv, Vp, M, C_, C_);

    // 3) causal flash attention
    dim3 agrid(T_ / 64, B_ * H_);  // (32, 32)
    attn_kernel<<<agrid, 256, 0, stream>>>(Qp, Kp, Vp, AOb);

    // 4) output projection (fp32 out to d_out)
    gemm_bt<0><<<ggrid, 256, 0, stream>>>(AOb, Wob, bo, (float*)d_out, M, C_, C_);
}

// Round 2
// 200.062 us; speedup vs baseline: 1.3329x; 1.3329x over previous
//
#include <hip/hip_runtime.h>
#include <hip/hip_bf16.h>
#include <cstdint>
#include <cstddef>

#define B_ 2
#define T_ 2048
#define C_ 1024
#define H_ 16
#define D_ 64

typedef unsigned short u16;
typedef unsigned int u32;

typedef __bf16 bf16x8 __attribute__((ext_vector_type(8)));
typedef float f32x4 __attribute__((ext_vector_type(4)));

union BFQ {
    uint4 q;
    bf16x8 v;
    u16 s[8];
};

__device__ __forceinline__ u16 f2bf(float f) {
    union { float f; u32 u; } x;
    x.f = f;
    u32 u = x.u;
    return (u16)((u + 0x7FFFu + ((u >> 16) & 1u)) >> 16);
}

__device__ __forceinline__ void gl_lds16(const u16* g, u16* l) {
    __builtin_amdgcn_global_load_lds(
        (const __attribute__((address_space(1))) u32*)g,
        (__attribute__((address_space(3))) u32*)l, 16, 0, 0);
}

// ---------------- fp32 -> bf16 conversion (vectorized) ----------------
__global__ void cvt_kernel(const float* __restrict__ in, u16* __restrict__ out, int n4) {
    int i = blockIdx.x * blockDim.x + threadIdx.x;
    int stride = gridDim.x * blockDim.x;
    for (; i < n4; i += stride) {
        float4 f = reinterpret_cast<const float4*>(in)[i];
        ushort4 o;
        o.x = f2bf(f.x);
        o.y = f2bf(f.y);
        o.z = f2bf(f.z);
        o.w = f2bf(f.w);
        reinterpret_cast<ushort4*>(out)[i] = o;
    }
}

// ---------------- GEMM (m97 structure): C[m,n] = sum_k A[m,k]*Bw[n,k] + bias[n]
// BM=128, BN=64, BK=64, 256 threads (4 waves as 2x2), linear LDS + global_load_lds w16.
template <int OUT_BF16>
__global__ __launch_bounds__(256, 2) void gemm_bt(const u16* __restrict__ A,
                                                  const u16* __restrict__ Bw,
                                                  const float* __restrict__ bias,
                                                  void* __restrict__ Cout,
                                                  int M, int N, int K) {
    __shared__ u16 As[128 * 64];
    __shared__ u16 Bs[64 * 64];

    const int tid = threadIdx.x;
    const int lane = tid & 63;
    const int wave = tid >> 6;
    const int wm = wave >> 1, wn = wave & 1;
    const int g = lane >> 4, r = lane & 15;
    const int m0 = blockIdx.y * 128, n0 = blockIdx.x * 64;

    f32x4 acc[4][2] = {};

    const int lrow = lane >> 3;
    const int lcol = (lane & 7) * 8;
    const u16* Abase = A + (size_t)(m0 + lrow) * K + lcol;
    const u16* Bbase = Bw + (size_t)(n0 + lrow) * K + lcol;

    for (int k0 = 0; k0 < K; k0 += 64) {
        __syncthreads();  // all waves done reading previous tile
#pragma unroll
        for (int c = 0; c < 4; ++c) {
            int ca = 4 * wave + c;
            gl_lds16(Abase + (size_t)(8 * ca) * K + k0, As + ca * 512);
        }
#pragma unroll
        for (int c = 0; c < 2; ++c) {
            int cb = 2 * wave + c;
            gl_lds16(Bbase + (size_t)(8 * cb) * K + k0, Bs + cb * 512);
        }
        __syncthreads();  // drains vmcnt -> LDS tiles ready

#pragma unroll
        for (int kk = 0; kk < 2; ++kk) {
            bf16x8 af[4], bfv[2];
#pragma unroll
            for (int mt = 0; mt < 4; ++mt) {
                BFQ u;
                u.q = *(const uint4*)(As + (wm * 64 + mt * 16 + r) * 64 + kk * 32 + g * 8);
                af[mt] = u.v;
            }
#pragma unroll
            for (int nt = 0; nt < 2; ++nt) {
                BFQ u;
                u.q = *(const uint4*)(Bs + (wn * 32 + nt * 16 + r) * 64 + kk * 32 + g * 8);
                bfv[nt] = u.v;
            }
#pragma unroll
            for (int mt = 0; mt < 4; ++mt)
#pragma unroll
                for (int nt = 0; nt < 2; ++nt)
                    acc[mt][nt] = __builtin_amdgcn_mfma_f32_16x16x32_bf16(af[mt], bfv[nt], acc[mt][nt], 0, 0, 0);
        }
    }

#pragma unroll
    for (int mt = 0; mt < 4; ++mt) {
#pragma unroll
        for (int nt = 0; nt < 2; ++nt) {
            int n = n0 + wn * 32 + nt * 16 + r;
            float bv = bias[n];
#pragma unroll
            for (int j = 0; j < 4; ++j) {
                int m = m0 + wm * 64 + mt * 16 + g * 4 + j;
                float val = acc[mt][nt][j] + bv;
                if (OUT_BF16)
                    ((u16*)Cout)[(size_t)m * N + n] = f2bf(val);
                else
                    ((float*)Cout)[(size_t)m * N + n] = val;
            }
        }
    }
}

// ---------------- causal flash attention, paired q-tiles ----------------
// grid: (16, B*H). block handles q-tiles i (A, light) and 31-i (B, heavy).
// 4 waves; each wave owns 16 q-rows of EACH tile. KV tile = 64.
// K read directly from global (L2-resident). V transposed into swizzled LDS.

__device__ __forceinline__ void softmax_step(const f32x4* s, int domask, int kv0, int qrow0,
                                             int g, int r, float* m_run, float* l_run,
                                             f32x4* o_acc, u16* pl) {
    float sv[4][4];
#pragma unroll
    for (int nt = 0; nt < 4; ++nt) {
#pragma unroll
        for (int j = 0; j < 4; ++j) {
            float x = s[nt][j] * 0.125f;
            if (domask) {
                int kg = kv0 + nt * 16 + r;
                int qg = qrow0 + g * 4 + j;
                x = (kg <= qg) ? x : -1e30f;
            }
            sv[nt][j] = x;
        }
    }
#pragma unroll
    for (int j = 0; j < 4; ++j) {
        float rm = fmaxf(fmaxf(sv[0][j], sv[1][j]), fmaxf(sv[2][j], sv[3][j]));
        rm = fmaxf(rm, __shfl_xor(rm, 1));
        rm = fmaxf(rm, __shfl_xor(rm, 2));
        rm = fmaxf(rm, __shfl_xor(rm, 4));
        rm = fmaxf(rm, __shfl_xor(rm, 8));
        float mnew = fmaxf(m_run[j], rm);
        float fac = __expf(m_run[j] - mnew);
        float p0 = __expf(sv[0][j] - mnew);
        float p1 = __expf(sv[1][j] - mnew);
        float p2 = __expf(sv[2][j] - mnew);
        float p3 = __expf(sv[3][j] - mnew);
        float rs = (p0 + p1) + (p2 + p3);
        rs += __shfl_xor(rs, 1);
        rs += __shfl_xor(rs, 2);
        rs += __shfl_xor(rs, 4);
        rs += __shfl_xor(rs, 8);
        l_run[j] = l_run[j] * fac + rs;
        m_run[j] = mnew;
#pragma unroll
        for (int nt = 0; nt < 4; ++nt) o_acc[nt][j] *= fac;
        // write P row q=g*4+j, swizzled stride-64: elem = (q*64 + kv) ^ ((q&7)<<3)
        int q = g * 4 + j;
        int sw = (q & 7) << 3;
        pl[(q * 64 + 0 * 16 + r) ^ sw] = f2bf(p0);
        pl[(q * 64 + 1 * 16 + r) ^ sw] = f2bf(p1);
        pl[(q * 64 + 2 * 16 + r) ^ sw] = f2bf(p2);
        pl[(q * 64 + 3 * 16 + r) ^ sw] = f2bf(p3);
    }
}

__global__ __launch_bounds__(256, 2) void attn_kernel(const u16* __restrict__ Qp,
                                                      const u16* __restrict__ Kp,
                                                      const u16* __restrict__ Vp,
                                                      u16* __restrict__ Op) {
    __shared__ u16 Vt[64 * 64];        // [d][kv], XOR-swizzled
    __shared__ u16 Pl[4][2][16 * 64];  // [wave][tile: 0=B,1=A][q][kv], XOR-swizzled

    const int tid = threadIdx.x, lane = tid & 63, wave = tid >> 6;
    const int g = lane >> 4, r = lane & 15;
    const int bh = blockIdx.y, b = bh >> 4, h = bh & 15;
    const int i = blockIdx.x;
    const int qA0 = i * 64;           // light tile
    const int qB0 = (31 - i) * 64;    // heavy tile

    const u16* Qbh = Qp + ((size_t)b * T_) * C_ + h * 64;
    const u16* Kbh = Kp + ((size_t)b * T_) * C_ + h * 64;
    const u16* Vbh = Vp + ((size_t)b * T_) * C_ + h * 64;
    u16* Obh = Op + ((size_t)b * T_) * C_ + h * 64;

    // hoist Q fragments (A-frag row = r -> q row = q0 + wave*16 + r)
    bf16x8 aqA[2], aqB[2];
    {
        const u16* qa = Qbh + (size_t)(qA0 + wave * 16 + r) * C_ + g * 8;
        const u16* qb = Qbh + (size_t)(qB0 + wave * 16 + r) * C_ + g * 8;
        BFQ u0, u1, u2, u3;
        u0.q = *(const uint4*)(qa);
        u1.q = *(const uint4*)(qa + 32);
        u2.q = *(const uint4*)(qb);
        u3.q = *(const uint4*)(qb + 32);
        aqA[0] = u0.v; aqA[1] = u1.v;
        aqB[0] = u2.v; aqB[1] = u3.v;
    }

    float mA[4], lA[4], mB[4], lB[4];
    f32x4 oA[4] = {}, oB[4] = {};
#pragma unroll
    for (int j = 0; j < 4; ++j) {
        mA[j] = -1e30f; lA[j] = 0.f;
        mB[j] = -1e30f; lB[j] = 0.f;
    }

    // V staging map: thread -> kv pair p = tid&31 (rows 2p,2p+1), d block = (tid>>5)*8
    const int vp = tid & 31;
    const int vd0 = (tid >> 5) * 8;

    for (int kv0 = 0; kv0 <= qB0; kv0 += 64) {
        const int actA = (kv0 <= qA0);
        __syncthreads();  // previous tile's Vt reads complete

        // stage V transposed (pairs along kv), XOR-swizzled
        {
            const u16* vr0 = Vbh + (size_t)(kv0 + 2 * vp) * C_ + vd0;
            BFQ va, vb;
            va.q = *(const uint4*)(vr0);
            vb.q = *(const uint4*)(vr0 + C_);
#pragma unroll
            for (int ii = 0; ii < 8; ++ii) {
                int d = vd0 + ii;
                u32 pr = (u32)va.s[ii] | ((u32)vb.s[ii] << 16);
                *(u32*)&Vt[(d * 64 + 2 * vp) ^ ((d & 7) << 3)] = pr;
            }
        }

        // K fragments straight from global (B-frag: col kv = nt*16+r, k = kk*32+g*8)
        bf16x8 kf[2][4];
#pragma unroll
        for (int kk = 0; kk < 2; ++kk)
#pragma unroll
            for (int nt = 0; nt < 4; ++nt) {
                BFQ u;
                u.q = *(const uint4*)(Kbh + (size_t)(kv0 + nt * 16 + r) * C_ + kk * 32 + g * 8);
                kf[kk][nt] = u.v;
            }
        __syncthreads();  // Vt visible (and K loads drained)

        // QK^T
        f32x4 sB[4] = {};
#pragma unroll
        for (int kk = 0; kk < 2; ++kk)
#pragma unroll
            for (int nt = 0; nt < 4; ++nt)
                sB[nt] = __builtin_amdgcn_mfma_f32_16x16x32_bf16(aqB[kk], kf[kk][nt], sB[nt], 0, 0, 0);
        f32x4 sA[4] = {};
        if (actA) {
#pragma unroll
            for (int kk = 0; kk < 2; ++kk)
#pragma unroll
                for (int nt = 0; nt < 4; ++nt)
                    sA[nt] = __builtin_amdgcn_mfma_f32_16x16x32_bf16(aqA[kk], kf[kk][nt], sA[nt], 0, 0, 0);
        }

        softmax_step(sB, kv0 == qB0, kv0, qB0 + wave * 16, g, r, mB, lB, oB, Pl[wave][0]);
        if (actA)
            softmax_step(sA, kv0 == qA0, kv0, qA0 + wave * 16, g, r, mA, lA, oA, Pl[wave][1]);

        asm volatile("s_waitcnt lgkmcnt(0)" ::: "memory");

        // V fragments (shared by both q-tiles)
        bf16x8 vf[2][4];
#pragma unroll
        for (int kk = 0; kk < 2; ++kk)
#pragma unroll
            for (int nt = 0; nt < 4; ++nt) {
                int d = nt * 16 + r;
                BFQ u;
                u.q = *(const uint4*)&Vt[(d * 64 + kk * 32 + g * 8) ^ ((d & 7) << 3)];
                vf[kk][nt] = u.v;
            }

        // PV for B
#pragma unroll
        for (int kk = 0; kk < 2; ++kk) {
            BFQ ua;
            ua.q = *(const uint4*)&Pl[wave][0][(r * 64 + kk * 32 + g * 8) ^ ((r & 7) << 3)];
#pragma unroll
            for (int nt = 0; nt < 4; ++nt)
                oB[nt] = __builtin_amdgcn_mfma_f32_16x16x32_bf16(ua.v, vf[kk][nt], oB[nt], 0, 0, 0);
        }
        // PV for A
        if (actA) {
#pragma unroll
            for (int kk = 0; kk < 2; ++kk) {
                BFQ ua;
                ua.q = *(const uint4*)&Pl[wave][1][(r * 64 + kk * 32 + g * 8) ^ ((r & 7) << 3)];
#pragma unroll
                for (int nt = 0; nt < 4; ++nt)
                    oA[nt] = __builtin_amdgcn_mfma_f32_16x16x32_bf16(ua.v, vf[kk][nt], oA[nt], 0, 0, 0);
            }
        }
    }

    // epilogue
#pragma unroll
    for (int nt = 0; nt < 4; ++nt) {
#pragma unroll
        for (int j = 0; j < 4; ++j) {
            int qgB = qB0 + wave * 16 + g * 4 + j;
            Obh[(size_t)qgB * C_ + nt * 16 + r] = f2bf(oB[nt][j] / lB[j]);
            int qgA = qA0 + wave * 16 + g * 4 + j;
            Obh[(size_t)qgA * C_ + nt * 16 + r] = f2bf(oA[nt][j] / lA[j]);
        }
    }
}

// ---------------- launcher ----------------
extern "C" void kernel_launch(void* const* d_in, const int* in_sizes, int n_in,
                              void* d_out, int out_size, void* d_ws, size_t ws_size,
                              hipStream_t stream) {
    const float* q = (const float*)d_in[0];
    const float* k = (const float*)d_in[1];
    const float* v = (const float*)d_in[2];
    // d_in[3] = mask (tril, known causal) - unused
    const float* Wq = (const float*)d_in[4];
    const float* bq = (const float*)d_in[5];
    const float* Wk = (const float*)d_in[6];
    const float* bk = (const float*)d_in[7];
    const float* Wv = (const float*)d_in[8];
    const float* bv = (const float*)d_in[9];
    const float* Wo = (const float*)d_in[10];
    const float* bo = (const float*)d_in[11];

    const size_t NTC = (size_t)B_ * T_ * C_;  // 4,194,304
    const size_t NW = (size_t)C_ * C_;        // 1,048,576

    char* ws = (char*)d_ws;
    size_t off = 0;
    u16* qb = (u16*)(ws + off);  off += NTC * 2;
    u16* kb = (u16*)(ws + off);  off += NTC * 2;
    u16* vb = (u16*)(ws + off);  off += NTC * 2;
    u16* Wqb = (u16*)(ws + off); off += NW * 2;
    u16* Wkb = (u16*)(ws + off); off += NW * 2;
    u16* Wvb = (u16*)(ws + off); off += NW * 2;
    u16* Wob = (u16*)(ws + off); off += NW * 2;
    u16* Qp = (u16*)(ws + off);  off += NTC * 2;
    u16* Kp = (u16*)(ws + off);  off += NTC * 2;
    u16* Vp = (u16*)(ws + off);  off += NTC * 2;
    u16* AOb = (u16*)(ws + off); off += NTC * 2;

    cvt_kernel<<<1024, 256, 0, stream>>>(q, qb, (int)(NTC / 4));
    cvt_kernel<<<1024, 256, 0, stream>>>(k, kb, (int)(NTC / 4));
    cvt_kernel<<<1024, 256, 0, stream>>>(v, vb, (int)(NTC / 4));
    cvt_kernel<<<1024, 256, 0, stream>>>(Wq, Wqb, (int)(NW / 4));
    cvt_kernel<<<1024, 256, 0, stream>>>(Wk, Wkb, (int)(NW / 4));
    cvt_kernel<<<1024, 256, 0, stream>>>(Wv, Wvb, (int)(NW / 4));
    cvt_kernel<<<1024, 256, 0, stream>>>(Wo, Wob, (int)(NW / 4));

    const int M = B_ * T_;  // 4096
    dim3 ggrid(C_ / 64, M / 128);  // (16, 32) = 512 blocks

    gemm_bt<1><<<ggrid, 256, 0, stream>>>(qb, Wqb, bq, Qp, M, C_, C_);
    gemm_bt<1><<<ggrid, 256, 0, stream>>>(kb, Wkb, bk, Kp, M, C_, C_);
    gemm_bt<1><<<ggrid, 256, 0, stream>>>(vb, Wvb, bv, Vp, M, C_, C_);

    dim3 agrid(16, B_ * H_);  // paired q-tiles: 16 x 32 = 512 blocks
    attn_kernel<<<agrid, 256, 0, stream>>>(Qp, Kp, Vp, AOb);

    gemm_bt<0><<<ggrid, 256, 0, stream>>>(AOb, Wob, bo, (float*)d_out, M, C_, C_);
}

// Round 3
// 157.733 us; speedup vs baseline: 1.6906x; 1.2684x over previous
//
#include <hip/hip_runtime.h>
#include <hip/hip_bf16.h>
#include <cstdint>
#include <cstddef>

#define B_ 2
#define T_ 2048
#define C_ 1024
#define H_ 16
#define D_ 64

typedef unsigned short u16;
typedef unsigned int u32;

typedef __bf16 bf16x8 __attribute__((ext_vector_type(8)));
typedef float f32x4 __attribute__((ext_vector_type(4)));

union BFQ {
    uint4 q;
    bf16x8 v;
    u16 s[8];
};

__device__ __forceinline__ u16 f2bf(float f) {
    union { float f; u32 u; } x;
    x.f = f;
    u32 u = x.u;
    return (u16)((u + 0x7FFFu + ((u >> 16) & 1u)) >> 16);
}

__device__ __forceinline__ void gl_lds16(const u16* g, u16* l) {
    __builtin_amdgcn_global_load_lds(
        (const __attribute__((address_space(1))) u32*)g,
        (__attribute__((address_space(3))) u32*)l, 16, 0, 0);
}

// ---------------- fp32 -> bf16 conversions (fused, vectorized) ----------------
__global__ void cvt3_kernel(const float* __restrict__ i0, const float* __restrict__ i1,
                            const float* __restrict__ i2, u16* __restrict__ o0,
                            u16* __restrict__ o1, u16* __restrict__ o2, int n4) {
    const float* in = blockIdx.z == 0 ? i0 : (blockIdx.z == 1 ? i1 : i2);
    u16* out = blockIdx.z == 0 ? o0 : (blockIdx.z == 1 ? o1 : o2);
    int i = blockIdx.x * blockDim.x + threadIdx.x;
    int stride = gridDim.x * blockDim.x;
    for (; i < n4; i += stride) {
        float4 f = reinterpret_cast<const float4*>(in)[i];
        ushort4 o;
        o.x = f2bf(f.x);
        o.y = f2bf(f.y);
        o.z = f2bf(f.z);
        o.w = f2bf(f.w);
        reinterpret_cast<ushort4*>(out)[i] = o;
    }
}

__global__ void cvt4_kernel(const float* __restrict__ i0, const float* __restrict__ i1,
                            const float* __restrict__ i2, const float* __restrict__ i3,
                            u16* __restrict__ o0, u16* __restrict__ o1,
                            u16* __restrict__ o2, u16* __restrict__ o3, int n4) {
    int z = blockIdx.z;
    const float* in = z == 0 ? i0 : (z == 1 ? i1 : (z == 2 ? i2 : i3));
    u16* out = z == 0 ? o0 : (z == 1 ? o1 : (z == 2 ? o2 : o3));
    int i = blockIdx.x * blockDim.x + threadIdx.x;
    int stride = gridDim.x * blockDim.x;
    for (; i < n4; i += stride) {
        float4 f = reinterpret_cast<const float4*>(in)[i];
        ushort4 o;
        o.x = f2bf(f.x);
        o.y = f2bf(f.y);
        o.z = f2bf(f.z);
        o.w = f2bf(f.w);
        reinterpret_cast<ushort4*>(out)[i] = o;
    }
}

// ---------------- GEMM body: C[m,n] = sum_k A[m,k]*Bw[n,k] + bias[n]
// BM=128, BN=64, BK=64. 2-phase double-buffered LDS (stage t+1 before compute t,
// one barrier per K-step). Both-sides XOR swizzle: LDS chunk (row, c) holds
// global chunk c ^ (row&7); staged via pre-swizzled per-lane global source.
template <int OUT_BF16>
__device__ __forceinline__ void gemm_body(const u16* __restrict__ A,
                                          const u16* __restrict__ Bw,
                                          const float* __restrict__ bias,
                                          void* __restrict__ Cout,
                                          int M, int N, int K) {
    __shared__ u16 As[2][128 * 64];
    __shared__ u16 Bs[2][64 * 64];

    const int tid = threadIdx.x;
    const int lane = tid & 63;
    const int wave = tid >> 6;
    const int wm = wave >> 1, wn = wave & 1;
    const int g = lane >> 4, r = lane & 15;
    const int m0 = blockIdx.y * 128, n0 = blockIdx.x * 64;

    f32x4 acc[4][2] = {};

    // staging source: lane covers (rowLocal = lane>>3, chunk = lane&7), but
    // fetches global chunk (lane&7) ^ (lane>>3)  [row&7 == lane>>3]
    const int lrow = lane >> 3;
    const int lcolS = ((lane & 7) ^ (lane >> 3)) * 8;
    const u16* Abase = A + (size_t)(m0 + lrow) * K + lcolS;
    const u16* Bbase = Bw + (size_t)(n0 + lrow) * K + lcolS;

    // prologue: stage k0=0 into buf 0
#pragma unroll
    for (int c = 0; c < 4; ++c) {
        int ca = 4 * wave + c;
        gl_lds16(Abase + (size_t)(8 * ca) * K, As[0] + ca * 512);
    }
#pragma unroll
    for (int c = 0; c < 2; ++c) {
        int cb = 2 * wave + c;
        gl_lds16(Bbase + (size_t)(8 * cb) * K, Bs[0] + cb * 512);
    }
    __syncthreads();

    int cur = 0;
    for (int k0 = 0; k0 < K; k0 += 64) {
        // stage next tile into the other buffer (overlaps with compute below)
        if (k0 + 64 < K) {
#pragma unroll
            for (int c = 0; c < 4; ++c) {
                int ca = 4 * wave + c;
                gl_lds16(Abase + (size_t)(8 * ca) * K + k0 + 64, As[cur ^ 1] + ca * 512);
            }
#pragma unroll
            for (int c = 0; c < 2; ++c) {
                int cb = 2 * wave + c;
                gl_lds16(Bbase + (size_t)(8 * cb) * K + k0 + 64, Bs[cur ^ 1] + cb * 512);
            }
        }

#pragma unroll
        for (int kk = 0; kk < 2; ++kk) {
            bf16x8 af[4], bfv[2];
#pragma unroll
            for (int mt = 0; mt < 4; ++mt) {
                int row = wm * 64 + mt * 16 + r;
                BFQ u;
                u.q = *(const uint4*)(As[cur] + row * 64 + (((kk * 4 + g) ^ (r & 7)) * 8));
                af[mt] = u.v;
            }
#pragma unroll
            for (int nt = 0; nt < 2; ++nt) {
                int row = wn * 32 + nt * 16 + r;
                BFQ u;
                u.q = *(const uint4*)(Bs[cur] + row * 64 + (((kk * 4 + g) ^ (r & 7)) * 8));
                bfv[nt] = u.v;
            }
            __builtin_amdgcn_s_setprio(1);
#pragma unroll
            for (int mt = 0; mt < 4; ++mt)
#pragma unroll
                for (int nt = 0; nt < 2; ++nt)
                    acc[mt][nt] = __builtin_amdgcn_mfma_f32_16x16x32_bf16(af[mt], bfv[nt], acc[mt][nt], 0, 0, 0);
            __builtin_amdgcn_s_setprio(0);
        }
        __syncthreads();  // drains vmcnt (next tile landed) + all waves done reading cur
        cur ^= 1;
    }

#pragma unroll
    for (int mt = 0; mt < 4; ++mt) {
#pragma unroll
        for (int nt = 0; nt < 2; ++nt) {
            int n = n0 + wn * 32 + nt * 16 + r;
            float bv = bias[n];
#pragma unroll
            for (int j = 0; j < 4; ++j) {
                int m = m0 + wm * 64 + mt * 16 + g * 4 + j;
                float val = acc[mt][nt][j] + bv;
                if (OUT_BF16)
                    ((u16*)Cout)[(size_t)m * N + n] = f2bf(val);
                else
                    ((float*)Cout)[(size_t)m * N + n] = val;
            }
        }
    }
}

// fused QKV projection: grid.z selects which of the 3 GEMMs
__global__ __launch_bounds__(256, 2) void gemm3_kernel(
    const u16* __restrict__ A0, const u16* __restrict__ A1, const u16* __restrict__ A2,
    const u16* __restrict__ W0, const u16* __restrict__ W1, const u16* __restrict__ W2,
    const float* __restrict__ b0, const float* __restrict__ b1, const float* __restrict__ b2,
    u16* __restrict__ C0, u16* __restrict__ C1, u16* __restrict__ C2,
    int M, int N, int K) {
    int z = blockIdx.z;
    const u16* A = z == 0 ? A0 : (z == 1 ? A1 : A2);
    const u16* W = z == 0 ? W0 : (z == 1 ? W1 : W2);
    const float* bias = z == 0 ? b0 : (z == 1 ? b1 : b2);
    u16* C = z == 0 ? C0 : (z == 1 ? C1 : C2);
    gemm_body<1>(A, W, bias, C, M, N, K);
}

__global__ __launch_bounds__(256, 2) void gemm_f32_kernel(const u16* __restrict__ A,
                                                          const u16* __restrict__ W,
                                                          const float* __restrict__ bias,
                                                          float* __restrict__ C,
                                                          int M, int N, int K) {
    gemm_body<0>(A, W, bias, C, M, N, K);
}

// ---------------- causal flash attention, paired q-tiles, pipelined ----------------
// grid: (16, B*H). block = 4 waves; q-tiles i (light, A) and 31-i (heavy, B);
// each wave owns 16 q-rows of each tile. K frags + V regs prefetched one KV-tile
// ahead (loads fly under softmax+PV). Raw s_barrier (no vmcnt drain).

__device__ __forceinline__ void softmax_step(f32x4* s, int domask, int kv0, int qrow0,
                                             int g, int r, float* m_run, float* l_run,
                                             f32x4* o_acc, u16* pl) {
    float sv[4][4];
#pragma unroll
    for (int nt = 0; nt < 4; ++nt) {
#pragma unroll
        for (int j = 0; j < 4; ++j) {
            float x = s[nt][j] * 0.125f;
            if (domask) {
                int kg = kv0 + nt * 16 + r;
                int qg = qrow0 + g * 4 + j;
                x = (kg <= qg) ? x : -1e30f;
            }
            sv[nt][j] = x;
        }
    }
    // per-row max (rows j, 16-lane column groups)
    float rm[4];
#pragma unroll
    for (int j = 0; j < 4; ++j) {
        float m = fmaxf(fmaxf(sv[0][j], sv[1][j]), fmaxf(sv[2][j], sv[3][j]));
        m = fmaxf(m, __shfl_xor(m, 1));
        m = fmaxf(m, __shfl_xor(m, 2));
        m = fmaxf(m, __shfl_xor(m, 4));
        m = fmaxf(m, __shfl_xor(m, 8));
        rm[j] = m;
    }
    // defer-max: skip rescale when max grew by <= 8 for ALL rows (wave-uniform)
    float grow = fmaxf(fmaxf(rm[0] - m_run[0], rm[1] - m_run[1]),
                       fmaxf(rm[2] - m_run[2], rm[3] - m_run[3]));
    float pout[4][4];
    float rs[4];
    if (__all(grow <= 8.0f)) {
#pragma unroll
        for (int j = 0; j < 4; ++j) {
            float mref = m_run[j];
            float p0 = __expf(sv[0][j] - mref);
            float p1 = __expf(sv[1][j] - mref);
            float p2 = __expf(sv[2][j] - mref);
            float p3 = __expf(sv[3][j] - mref);
            pout[0][j] = p0; pout[1][j] = p1; pout[2][j] = p2; pout[3][j] = p3;
            rs[j] = (p0 + p1) + (p2 + p3);
        }
    } else {
#pragma unroll
        for (int j = 0; j < 4; ++j) {
            float mnew = fmaxf(m_run[j], rm[j]);
            float fac = __expf(m_run[j] - mnew);
            float p0 = __expf(sv[0][j] - mnew);
            float p1 = __expf(sv[1][j] - mnew);
            float p2 = __expf(sv[2][j] - mnew);
            float p3 = __expf(sv[3][j] - mnew);
            pout[0][j] = p0; pout[1][j] = p1; pout[2][j] = p2; pout[3][j] = p3;
            rs[j] = (p0 + p1) + (p2 + p3);
            l_run[j] *= fac;
            m_run[j] = mnew;
#pragma unroll
            for (int nt = 0; nt < 4; ++nt) o_acc[nt][j] *= fac;
        }
    }
#pragma unroll
    for (int j = 0; j < 4; ++j) {
        float t = rs[j];
        t += __shfl_xor(t, 1);
        t += __shfl_xor(t, 2);
        t += __shfl_xor(t, 4);
        t += __shfl_xor(t, 8);
        l_run[j] += t;
        // write P row q=g*4+j, swizzled: elem = (q*64 + kv) ^ ((q&7)<<3)
        int q = g * 4 + j;
        int sw = (q & 7) << 3;
        pl[(q * 64 + 0 * 16 + r) ^ sw] = f2bf(pout[0][j]);
        pl[(q * 64 + 1 * 16 + r) ^ sw] = f2bf(pout[1][j]);
        pl[(q * 64 + 2 * 16 + r) ^ sw] = f2bf(pout[2][j]);
        pl[(q * 64 + 3 * 16 + r) ^ sw] = f2bf(pout[3][j]);
    }
}

__global__ __launch_bounds__(256, 2) void attn_kernel(const u16* __restrict__ Qp,
                                                      const u16* __restrict__ Kp,
                                                      const u16* __restrict__ Vp,
                                                      u16* __restrict__ Op) {
    __shared__ u16 Vt[64 * 64];        // [d][kv], XOR-swizzled
    __shared__ u16 Pl[4][2][16 * 64];  // [wave][tile: 0=B,1=A][q][kv], XOR-swizzled

    const int tid = threadIdx.x, lane = tid & 63, wave = tid >> 6;
    const int g = lane >> 4, r = lane & 15;
    const int bh = blockIdx.y, b = bh >> 4, h = bh & 15;
    const int i = blockIdx.x;
    const int qA0 = i * 64;           // light tile
    const int qB0 = (31 - i) * 64;    // heavy tile

    const u16* Qbh = Qp + ((size_t)b * T_) * C_ + h * 64;
    const u16* Kbh = Kp + ((size_t)b * T_) * C_ + h * 64;
    const u16* Vbh = Vp + ((size_t)b * T_) * C_ + h * 64;
    u16* Obh = Op + ((size_t)b * T_) * C_ + h * 64;

    // hoist Q fragments (A-frag row = r -> q row = q0 + wave*16 + r)
    bf16x8 aqA[2], aqB[2];
    {
        const u16* qa = Qbh + (size_t)(qA0 + wave * 16 + r) * C_ + g * 8;
        const u16* qb = Qbh + (size_t)(qB0 + wave * 16 + r) * C_ + g * 8;
        BFQ u0, u1, u2, u3;
        u0.q = *(const uint4*)(qa);
        u1.q = *(const uint4*)(qa + 32);
        u2.q = *(const uint4*)(qb);
        u3.q = *(const uint4*)(qb + 32);
        aqA[0] = u0.v; aqA[1] = u1.v;
        aqB[0] = u2.v; aqB[1] = u3.v;
    }

    float mA[4], lA[4], mB[4], lB[4];
    f32x4 oA[4] = {}, oB[4] = {};
#pragma unroll
    for (int j = 0; j < 4; ++j) {
        mA[j] = -1e30f; lA[j] = 0.f;
        mB[j] = -1e30f; lB[j] = 0.f;
    }

    // V staging map: kv pair vp (rows 2vp,2vp+1), d block = (tid>>5)*8
    const int vp = tid & 31;
    const int vd0 = (tid >> 5) * 8;

    // ---- prologue prefetch for kv0 = 0 ----
    BFQ kf[2][4];
#pragma unroll
    for (int kk = 0; kk < 2; ++kk)
#pragma unroll
        for (int nt = 0; nt < 4; ++nt)
            kf[kk][nt].q = *(const uint4*)(Kbh + (size_t)(nt * 16 + r) * C_ + kk * 32 + g * 8);
    BFQ va, vb;
    {
        const u16* vr0 = Vbh + (size_t)(2 * vp) * C_ + vd0;
        va.q = *(const uint4*)(vr0);
        vb.q = *(const uint4*)(vr0 + C_);
    }

    for (int kv0 = 0; kv0 <= qB0; kv0 += 64) {
        const int actA = (kv0 <= qA0);

        __builtin_amdgcn_s_barrier();  // prev iter's Vt reads complete everywhere

        // write Vt (transposed, swizzled) from prefetched regs
#pragma unroll
        for (int ii = 0; ii < 8; ++ii) {
            int d = vd0 + ii;
            u32 pr = (u32)va.s[ii] | ((u32)vb.s[ii] << 16);
            *(u32*)&Vt[(d * 64 + 2 * vp) ^ ((d & 7) << 3)] = pr;
        }

        // QK^T, both tiles, shared K fragments
        f32x4 sB[4] = {}, sA[4] = {};
        __builtin_amdgcn_s_setprio(1);
#pragma unroll
        for (int kk = 0; kk < 2; ++kk)
#pragma unroll
            for (int nt = 0; nt < 4; ++nt)
                sB[nt] = __builtin_amdgcn_mfma_f32_16x16x32_bf16(aqB[kk], kf[kk][nt].v, sB[nt], 0, 0, 0);
        if (actA) {
#pragma unroll
            for (int kk = 0; kk < 2; ++kk)
#pragma unroll
                for (int nt = 0; nt < 4; ++nt)
                    sA[nt] = __builtin_amdgcn_mfma_f32_16x16x32_bf16(aqA[kk], kf[kk][nt].v, sA[nt], 0, 0, 0);
        }
        __builtin_amdgcn_s_setprio(0);

        // prefetch next KV tile (flies under softmax + PV)
        if (kv0 + 64 <= qB0) {
            const u16* kn = Kbh + (size_t)(kv0 + 64) * C_;
#pragma unroll
            for (int kk = 0; kk < 2; ++kk)
#pragma unroll
                for (int nt = 0; nt < 4; ++nt)
                    kf[kk][nt].q = *(const uint4*)(kn + (size_t)(nt * 16 + r) * C_ + kk * 32 + g * 8);
            const u16* vr0 = Vbh + (size_t)(kv0 + 64 + 2 * vp) * C_ + vd0;
            va.q = *(const uint4*)(vr0);
            vb.q = *(const uint4*)(vr0 + C_);
        }

        softmax_step(sB, kv0 == qB0, kv0, qB0 + wave * 16, g, r, mB, lB, oB, Pl[wave][0]);
        if (actA)
            softmax_step(sA, kv0 == qA0, kv0, qA0 + wave * 16, g, r, mA, lA, oA, Pl[wave][1]);

        asm volatile("s_waitcnt lgkmcnt(0)" ::: "memory");  // my Vt + P writes committed
        __builtin_amdgcn_s_barrier();                       // everyone's Vt visible

        // V fragments (shared by both q-tiles)
        bf16x8 vf[2][4];
#pragma unroll
        for (int kk = 0; kk < 2; ++kk)
#pragma unroll
            for (int nt = 0; nt < 4; ++nt) {
                int d = nt * 16 + r;
                BFQ u;
                u.q = *(const uint4*)&Vt[(d * 64 + kk * 32 + g * 8) ^ ((d & 7) << 3)];
                vf[kk][nt] = u.v;
            }

        __builtin_amdgcn_s_setprio(1);
#pragma unroll
        for (int kk = 0; kk < 2; ++kk) {
            BFQ ua;
            ua.q = *(const uint4*)&Pl[wave][0][(r * 64 + kk * 32 + g * 8) ^ ((r & 7) << 3)];
#pragma unroll
            for (int nt = 0; nt < 4; ++nt)
                oB[nt] = __builtin_amdgcn_mfma_f32_16x16x32_bf16(ua.v, vf[kk][nt], oB[nt], 0, 0, 0);
        }
        if (actA) {
#pragma unroll
            for (int kk = 0; kk < 2; ++kk) {
                BFQ ua;
                ua.q = *(const uint4*)&Pl[wave][1][(r * 64 + kk * 32 + g * 8) ^ ((r & 7) << 3)];
#pragma unroll
                for (int nt = 0; nt < 4; ++nt)
                    oA[nt] = __builtin_amdgcn_mfma_f32_16x16x32_bf16(ua.v, vf[kk][nt], oA[nt], 0, 0, 0);
            }
        }
        __builtin_amdgcn_s_setprio(0);
    }

    // epilogue
#pragma unroll
    for (int nt = 0; nt < 4; ++nt) {
#pragma unroll
        for (int j = 0; j < 4; ++j) {
            int qgB = qB0 + wave * 16 + g * 4 + j;
            Obh[(size_t)qgB * C_ + nt * 16 + r] = f2bf(oB[nt][j] / lB[j]);
            int qgA = qA0 + wave * 16 + g * 4 + j;
            Obh[(size_t)qgA * C_ + nt * 16 + r] = f2bf(oA[nt][j] / lA[j]);
        }
    }
}

// ---------------- launcher ----------------
extern "C" void kernel_launch(void* const* d_in, const int* in_sizes, int n_in,
                              void* d_out, int out_size, void* d_ws, size_t ws_size,
                              hipStream_t stream) {
    const float* q = (const float*)d_in[0];
    const float* k = (const float*)d_in[1];
    const float* v = (const float*)d_in[2];
    // d_in[3] = mask (tril, known causal) - unused
    const float* Wq = (const float*)d_in[4];
    const float* bq = (const float*)d_in[5];
    const float* Wk = (const float*)d_in[6];
    const float* bk = (const float*)d_in[7];
    const float* Wv = (const float*)d_in[8];
    const float* bv = (const float*)d_in[9];
    const float* Wo = (const float*)d_in[10];
    const float* bo = (const float*)d_in[11];

    const size_t NTC = (size_t)B_ * T_ * C_;  // 4,194,304
    const size_t NW = (size_t)C_ * C_;        // 1,048,576

    char* ws = (char*)d_ws;
    size_t off = 0;
    u16* qb = (u16*)(ws + off);  off += NTC * 2;
    u16* kb = (u16*)(ws + off);  off += NTC * 2;
    u16* vb = (u16*)(ws + off);  off += NTC * 2;
    u16* Wqb = (u16*)(ws + off); off += NW * 2;
    u16* Wkb = (u16*)(ws + off); off += NW * 2;
    u16* Wvb = (u16*)(ws + off); off += NW * 2;
    u16* Wob = (u16*)(ws + off); off += NW * 2;
    u16* Qp = (u16*)(ws + off);  off += NTC * 2;
    u16* Kp = (u16*)(ws + off);  off += NTC * 2;
    u16* Vp = (u16*)(ws + off);  off += NTC * 2;
    u16* AOb = (u16*)(ws + off); off += NTC * 2;

    cvt3_kernel<<<dim3(512, 1, 3), 256, 0, stream>>>(q, k, v, qb, kb, vb, (int)(NTC / 4));
    cvt4_kernel<<<dim3(128, 1, 4), 256, 0, stream>>>(Wq, Wk, Wv, Wo, Wqb, Wkb, Wvb, Wob, (int)(NW / 4));

    const int M = B_ * T_;  // 4096
    dim3 g3(C_ / 64, M / 128, 3);  // (16, 32, 3) = 1536 blocks
    gemm3_kernel<<<g3, 256, 0, stream>>>(qb, kb, vb, Wqb, Wkb, Wvb, bq, bk, bv,
                                         Qp, Kp, Vp, M, C_, C_);

    dim3 agrid(16, B_ * H_);  // paired q-tiles: 16 x 32 = 512 blocks
    attn_kernel<<<agrid, 256, 0, stream>>>(Qp, Kp, Vp, AOb);

    dim3 g1(C_ / 64, M / 128, 1);
    gemm_f32_kernel<<<g1, 256, 0, stream>>>(AOb, Wob, bo, (float*)d_out, M, C_, C_);
}